// Round 15
// baseline (55.764 us; speedup 1.0000x reference)
//
#include <hip/hip_runtime.h>
#include <stdint.h>

// AnchorTargetLayer for MI355X — 3-dispatch windowed gather.
// N = 331776 anchors (192*192*9 grid), G = 128 gt boxes.
// anchor(row,col,s) = base[s] + 16*(col,row,col,row) exactly in fp32, and
// base[s] == all_anchors[s]. Only ~2% of anchor-gt pairs have inter > 0.
// Pipeline:
//   k_pre2   block u=(g,s): per-(gt,shape) window max -> PLAIN store
//            gt_max_s[u] (no atomics, no init); last block zeros scalars
//   k_work   1296 blocks = (16x16-cell tile) x (shape): per-anchor
//            best/argmax + INLINE tie test + label + RNG + fg list +
//            bg candidates. Per-shape tile gt-list (tighter than union).
//   k_output every block recomputes the exact lex cutoffs from the lists
//            (LDS-cached) then writes labels/targets/weights
// NOTE r9:  cooperative grid.sync() ~100us/sync on gfx950 — never.
// NOTE r11: per-block __threadfence() = L2-writeback storm (+80us/432 blks)
//           — kernel boundaries ARE the cheap fence.
// NOTE r12: serializing a small-grid pre-pass costs ~8us; keep pre-passes
//           wide (>=1000 blocks) and tiny.
// NOTE r15: gather at 432 blocks = 1.7 blocks/CU; 1296 blocks (per-shape)
//           for latency hiding.
#define TF_PARTITIONABLE 1

#define GMAX 128
#define FG_CAP 8192
#define BGC_CAP 8192
#define LDS_CAP 2048
#define T1 0.00390625f        // bg candidate threshold = 1/256
                              // cutoff quantile ~256/200k=0.0013; candidates
                              // ~Binom(200k,1/256)=781±28 -> 18 sigma >= k_b
#define RPN_NEG 0.3f
#define RPN_POS 0.7f

struct U2 { uint32_t a, b; };

__host__ __device__ constexpr U2 tf2x32(uint32_t k0, uint32_t k1, uint32_t x0, uint32_t x1) {
  uint32_t ks2 = k0 ^ k1 ^ 0x1BD11BDAu;
  x0 += k0; x1 += k1;
#define TFR(r) { x0 += x1; x1 = (uint32_t)((x1 << (r)) | (x1 >> (32 - (r)))); x1 ^= x0; }
  TFR(13) TFR(15) TFR(26) TFR(6)
  x0 += k1; x1 += ks2 + 1u;
  TFR(17) TFR(29) TFR(16) TFR(24)
  x0 += ks2; x1 += k0 + 2u;
  TFR(13) TFR(15) TFR(26) TFR(6)
  x0 += k0; x1 += k1 + 3u;
  TFR(17) TFR(29) TFR(16) TFR(24)
  x0 += k1; x1 += ks2 + 4u;
  TFR(13) TFR(15) TFR(26) TFR(6)
  x0 += ks2; x1 += k0 + 5u;
#undef TFR
  return U2{x0, x1};
}

#if TF_PARTITIONABLE
constexpr U2 KEYF = tf2x32(0u, 42u, 0u, 0u);
constexpr U2 KEYB = tf2x32(0u, 42u, 0u, 1u);
#else
constexpr U2 C02 = tf2x32(0u, 42u, 0u, 2u);
constexpr U2 C13 = tf2x32(0u, 42u, 1u, 3u);
constexpr U2 KEYF = U2{C02.a, C13.a};
constexpr U2 KEYB = U2{C02.b, C13.b};
#endif

__device__ __forceinline__ float tf_uniform(uint32_t k0, uint32_t k1, uint32_t i, uint32_t N) {
#if TF_PARTITIONABLE
  U2 r = tf2x32(k0, k1, 0u, i);
  uint32_t bits = r.a ^ r.b;
#else
  uint32_t h = N >> 1;
  uint32_t bits;
  if (i < h) { U2 r = tf2x32(k0, k1, i, i + h); bits = r.a; }
  else       { U2 r = tf2x32(k0, k1, i - h, i); bits = r.b; }
#endif
  return __uint_as_float((bits >> 9) | 0x3f800000u) - 1.0f;
}

// window of cells where inter COULD be >0 for box B vs gt, with ±1 slack
__device__ __forceinline__ void window(float4 B, float gx1, float gy1, float gx2, float gy2,
                                       int W, int H, int& c0, int& c1, int& r0, int& r1) {
  c0 = (int)floorf((gx1 - 1.0f - B.z) * 0.0625f) - 1; if (c0 < 0) c0 = 0;
  c1 = (int)ceilf ((gx2 + 1.0f - B.x) * 0.0625f) + 1; if (c1 > W - 1) c1 = W - 1;
  r0 = (int)floorf((gy1 - 1.0f - B.w) * 0.0625f) - 1; if (r0 < 0) r0 = 0;
  r1 = (int)ceilf ((gy2 + 1.0f - B.y) * 0.0625f) + 1; if (r1 > H - 1) r1 = H - 1;
}

// wave-aggregated append slot: 1 LDS atomic per wave; all lanes must call
__device__ __forceinline__ uint32_t waveAppend(uint32_t* lds_cnt, bool pred) {
  unsigned long long m = __ballot(pred);
  uint32_t my = 0u;
  if (m) {
    int lane = (int)(threadIdx.x & 63);
    int lead = __ffsll(m) - 1;
    uint32_t rank = (uint32_t)__popcll(m & ((1ull << lane) - 1ull));
    uint32_t base = 0u;
    if (lane == lead) base = atomicAdd(lds_cnt, (uint32_t)__popcll(m));
    base = __shfl(base, lead);
    my = base + rank;
  }
  return my;
}

// scalars layout (u32): 0 F | 1 B | 2 bgcCnt

// K1: blocks [0, G*A) = per-(gt,shape) window max, PLAIN store (no init);
//     block G*A zeros scalars.
__global__ __launch_bounds__(256) void k_pre2(const float4* __restrict__ anchors,
    const float* __restrict__ gt, const float* __restrict__ im_info,
    int W, int H, int A, int G,
    float* __restrict__ gt_max_s, uint32_t* __restrict__ scalars) {
#pragma clang fp contract(off)
  int t = threadIdx.x;
  if (blockIdx.x == (unsigned)(G * A)) {
    if (t < 32) scalars[t] = 0u;
    return;
  }
  int g = blockIdx.x / A, s = blockIdx.x % A;
  float4 B = anchors[s];
  float gx1 = gt[g*5], gy1 = gt[g*5+1], gx2 = gt[g*5+2], gy2 = gt[g*5+3];
  float ga = (gx2 - gx1 + 1.0f) * (gy2 - gy1 + 1.0f);
  float aa = (B.z - B.x + 1.0f) * (B.w - B.y + 1.0f);
  float imH = im_info[0], imW = im_info[1];
  int c0, c1, r0, r1;
  window(B, gx1, gy1, gx2, gy2, W, H, c0, c1, r0, r1);
  float m = -1.0f;
  if (c1 >= c0 && r1 >= r0) {
    int wc = c1 - c0 + 1, tot = wc * (r1 - r0 + 1);
    for (int idx = t; idx < tot; idx += 256) {
      int row = r0 + idx / wc, col = c0 + idx % wc;
      float fx = 16.0f * (float)col, fy = 16.0f * (float)row;
      float ax = B.x + fx, ay = B.y + fy, az = B.z + fx, aw = B.w + fy;
      if (!(ax >= 0.0f && ay >= 0.0f && az < imW && aw < imH)) continue;
      float iwr = fminf(az, gx2) - fmaxf(ax, gx1) + 1.0f;
      float ihr = fminf(aw, gy2) - fmaxf(ay, gy1) + 1.0f;
      if (iwr > 0.0f && ihr > 0.0f) {
        float inter = iwr * ihr;                      // clamped product (both >0)
        m = fmaxf(m, inter / ((aa + ga) - inter));    // reference bit sequence
      }
    }
  }
#pragma unroll
  for (int d = 1; d < 64; d <<= 1) m = fmaxf(m, __shfl_xor(m, d));
  __shared__ float wm[4];
  if ((t & 63) == 0) wm[t >> 6] = m;
  __syncthreads();
  if (t == 0)
    gt_max_s[blockIdx.x] = fmaxf(fmaxf(wm[0], wm[1]), fmaxf(wm[2], wm[3]));
}

// K2: 1296 blocks = tile x shape; thread = one cell, one shape. Per-shape
// tile gt-list (a gt outside shape s's window has v=0 everywhere in the
// tile: can't update best (0>0 false) nor tie (gm>0)). Inline tie; NO tail.
__global__ __launch_bounds__(256) void k_work(const float4* __restrict__ anchors,
    const float* __restrict__ gt, const float* __restrict__ im_info,
    int W, int H, int A, int G, int N, int ntx,
    int* __restrict__ amax, int8_t* __restrict__ label,
    const float* __restrict__ gt_max_s, uint32_t* __restrict__ scalars,
    int* __restrict__ fgIdx, float* __restrict__ fgVal,
    int* __restrict__ bgcIdx, float* __restrict__ bgcVal) {
#pragma clang fp contract(off)
  __shared__ float4 sgt4[GMAX];
  __shared__ float sga[GMAX];
  __shared__ float sgm[GMAX];
  __shared__ int slist[GMAX];
  __shared__ uint32_t wcnt[4];
  __shared__ uint32_t lcnt[3], lbase[2];   // 0 fg, 1 bg-cand, 2 bg total
  int t = threadIdx.x;
  int tile = blockIdx.x / A, s = blockIdx.x % A;
  int tc = tile % ntx, tr = tile / ntx;
  float imH = im_info[0], imW = im_info[1];
  if (t < 3) lcnt[t] = 0u;
  float4 B = anchors[s];                        // uniform address -> broadcast
  float aab = (B.z - B.x + 1.0f) * (B.w - B.y + 1.0f);
  __syncthreads();
  // per-(tile,shape) gt list, ballot-compacted ascending
  bool fl = false;
  if (t < G) {
    int c0, c1, r0, r1;
    window(B, gt[t*5], gt[t*5+1], gt[t*5+2], gt[t*5+3], W, H, c0, c1, r0, r1);
    fl = (c1 >= c0 && r1 >= r0 &&
          c0 <= tc*16+15 && c1 >= tc*16 && r0 <= tr*16+15 && r1 >= tr*16);
  }
  unsigned long long bm = __ballot(fl);
  int wv = t >> 6, ln = t & 63;
  if (ln == 0) wcnt[wv] = (uint32_t)__popcll(bm);
  __syncthreads();
  int cnt = (int)(wcnt[0] + wcnt[1]);     // G <= 128
  if (fl) {
    uint32_t base = (wv == 1) ? wcnt[0] : 0u;
    uint32_t rank = (uint32_t)__popcll(bm & ((1ull << ln) - 1ull));
    slist[base + rank] = t;
  }
  __syncthreads();
  for (int q = t; q < cnt; q += 256) {
    int g = slist[q];
    float x1 = gt[g*5], y1 = gt[g*5+1], x2 = gt[g*5+2], y2 = gt[g*5+3];
    sgt4[q] = make_float4(x1, y1, x2, y2);
    sga[q] = (x2 - x1 + 1.0f) * (y2 - y1 + 1.0f);
    // fold per-shape maxima: fmaxf exactly associative -> bit-identical
    float gm = gt_max_s[g * A];
    for (int s2 = 1; s2 < A; ++s2) gm = fmaxf(gm, gt_max_s[g * A + s2]);
    sgm[q] = gm;
  }
  __syncthreads();

  int col = tc * 16 + (t & 15), row = tr * 16 + (t >> 4);
  bool validCell = (col < W) && (row < H);
  float fx = 16.0f * (float)col, fy = 16.0f * (float)row;   // exact integers
  if (!validCell) { fx = -1.0e9f; fy = -1.0e9f; }
  float ax = B.x + fx, ay = B.y + fy;       // == reference anchor bits
  float az = B.z + fx, aw = B.w + fy;
  bool ins = (ax >= 0.0f && ay >= 0.0f && az < imW && aw < imH);
  float best = 0.0f;                        // all-zero row -> argmax 0 (ref)
  int am = 0;
  bool tie = false;
  for (int q = 0; q < cnt; ++q) {           // ascending g: first-max rule
    float4 G4 = sgt4[q];
    float ga = sga[q];
    float gm = sgm[q];
    int g = slist[q];
    float iwr = fminf(az, G4.z) - fmaxf(ax, G4.x) + 1.0f;
    float ihr = fminf(aw, G4.w) - fmaxf(ay, G4.y) + 1.0f;
    float inter = fmaxf(iwr, 0.0f) * fmaxf(ihr, 0.0f);
    float v = inter / ((aab + ga) - inter);  // inter==0 -> v==+0.0 exact
    if (v > best) { best = v; am = g; }
    tie |= (v == gm);                        // is_best: v matches col max
  }
  // finalize: label (quirk order), amax, RNG, list appends
  int i = (row * W + col) * A + s;
  int lab = -1;
  if (ins) {
    if (best < RPN_NEG) lab = 0;
    if (tie) lab = -lab;                    // -1 -> 1 ; 0 stays 0 (quirk)
    if (best >= RPN_POS) lab = 1;
  }
  bool isf = validCell && (lab == 1);
  bool isb = validCell && (lab == 0);
  if (validCell) { label[i] = (int8_t)lab; amax[i] = am; }
  float val = 0.0f;
  if (isf) val = tf_uniform(KEYF.a, KEYF.b, (uint32_t)i, (uint32_t)N);
  if (isb) val = tf_uniform(KEYB.a, KEYB.b, (uint32_t)i, (uint32_t)N);
  bool cand = isb && (val < T1);
  unsigned long long mb = __ballot(isb);     // bg total via ballot count
  if ((t & 63) == 0 && mb) atomicAdd(&lcnt[2], (uint32_t)__popcll(mb));
  uint32_t mf = waveAppend(&lcnt[0], isf);
  uint32_t mc = waveAppend(&lcnt[1], cand);
  __syncthreads();
  if (t == 0) {
    lbase[0] = lcnt[0] ? atomicAdd(&scalars[0], lcnt[0]) : 0u;
    lbase[1] = lcnt[1] ? atomicAdd(&scalars[2], lcnt[1]) : 0u;
    if (lcnt[2]) atomicAdd(&scalars[1], lcnt[2]);
  }
  __syncthreads();
  if (isf) {
    uint32_t p = lbase[0] + mf;
    if (p < FG_CAP) { fgIdx[p] = i; fgVal[p] = val; }
  } else if (cand) {
    uint32_t p = lbase[1] + mc;
    if (p < BGC_CAP) { bgcIdx[p] = i; bgcVal[p] = val; }
  }
}

// K3: every block recomputes the exact lex cutoffs (deterministic; lists
// LDS-cached when <= LDS_CAP entries), then writes labels/targets/weights.
__global__ __launch_bounds__(256) void k_output(const float4* __restrict__ anchors,
    const float* __restrict__ gt, const float* __restrict__ im_info, int N,
    const int* __restrict__ amax, const int8_t* __restrict__ label,
    const uint32_t* __restrict__ scalars,
    const int* __restrict__ fgIdx, const float* __restrict__ fgVal,
    const int* __restrict__ bgcIdx, const float* __restrict__ bgcVal,
    float* __restrict__ out) {
#pragma clang fp contract(off)
  __shared__ float lv[LDS_CAP];
  __shared__ int   li[LDS_CAP];
  __shared__ uint32_t hist[256];
  __shared__ int binT; __shared__ uint32_t baseT;
  __shared__ int mcnt;
  __shared__ float mv[256]; __shared__ int mi[256]; __shared__ uint32_t mr[256];
  __shared__ float s_cv[2]; __shared__ int s_ci[2]; __shared__ float s_inv;
  int t = threadIdx.x;
  uint32_t F = scalars[0], B = scalars[1];
  uint32_t k_f = F > 128u ? 128u : F;
  uint32_t k_b = 256u - k_f;
  if (t == 0) {
    uint32_t kept = k_f + (B < k_b ? B : k_b);
    s_inv = kept ? (1.0f / (float)kept) : 0.0f;       // 1/num_ex
    s_cv[0] = __uint_as_float(0x7f800000u); s_ci[0] = 0x7fffffff;  // keep-all
    s_cv[1] = __uint_as_float(0x7f800000u); s_ci[1] = 0x7fffffff;
  }
  __syncthreads();
  for (int pass = 0; pass < 2; ++pass) {
    const float* gvals = pass ? bgcVal : fgVal;
    const int*   gidxs = pass ? bgcIdx : fgIdx;
    uint32_t tot = pass ? B : F;
    uint32_t kk  = pass ? k_b : k_f;
    uint32_t rawn = pass ? scalars[2] : F;
    uint32_t cap  = pass ? (uint32_t)BGC_CAP : (uint32_t)FG_CAP;
    int n = (int)(rawn > cap ? cap : rawn);
    float scale = pass ? (256.0f / T1) : 256.0f;
    bool need = (tot > kk) && (kk > 0u) && ((uint32_t)n >= kk);
    bool useLds = need && (n <= LDS_CAP);
    if (useLds)
      for (int j = t; j < n; j += 256) { lv[j] = gvals[j]; li[j] = gidxs[j]; }
    const float* vals = useLds ? (const float*)lv : gvals;
    const int*   idxs = useLds ? (const int*)li : gidxs;
    hist[t] = 0u;
    if (t == 0) { mcnt = 0; binT = -1; baseT = 0u; }
    __syncthreads();
    if (need)
      for (int j = t; j < n; j += 256) {
        int b = (int)(vals[j] * scale); if (b > 255) b = 255;
        atomicAdd(&hist[b], 1u);
      }
    __syncthreads();
    if (need && t == 0) {
      uint32_t c = 0;
      for (int b = 0; b < 256; ++b) {
        if (c + hist[b] >= kk) { binT = b; baseT = c; break; }
        c += hist[b];
      }
    }
    __syncthreads();
    if (need)
      for (int j = t; j < n; j += 256) {
        int b = (int)(vals[j] * scale); if (b > 255) b = 255;
        if (b == binT) {
          int p = atomicAdd(&mcnt, 1);
          if (p < 256) { mv[p] = vals[j]; mi[p] = idxs[j]; }
        }
      }
    __syncthreads();
    int m = mcnt > 256 ? 256 : mcnt;
    if (t < m) mr[t] = baseT;
    __syncthreads();
    if (need)
      for (int j = t; j < n; j += 256) {
        float v = vals[j]; int i = idxs[j];
        int b = (int)(v * scale); if (b > 255) b = 255;
        if (b == binT)
          for (int q = 0; q < m; ++q)
            if (v < mv[q] || (v == mv[q] && i < mi[q])) atomicAdd(&mr[q], 1u);
      }
    __syncthreads();
    if (need && t < m && mr[t] == kk - 1u) { s_cv[pass] = mv[t]; s_ci[pass] = mi[t]; }
    __syncthreads();
  }

  float invw = s_inv;
  float cvF = s_cv[0]; int ciF = s_ci[0];
  float cvB = s_cv[1]; int ciB = s_ci[1];
  int i = blockIdx.x * 256 + t;
  if (i >= N) return;
  float4 a = anchors[i];
  float imH = im_info[0], imW = im_info[1];
  bool inside = (a.x >= 0.0f && a.y >= 0.0f && a.z < imW && a.w < imH);
  int lab = label[i];
  if (lab == 1) {                 // fg subsample: keep iff (v,i) <=lex cutF
    float v = tf_uniform(KEYF.a, KEYF.b, (uint32_t)i, (uint32_t)N);
    if (!(v < cvF || (v == cvF && i <= ciF))) lab = -1;
  } else if (lab == 0) {          // bg subsample
    float v = tf_uniform(KEYB.a, KEYB.b, (uint32_t)i, (uint32_t)N);
    if (!(v < cvB || (v == cvB && i <= ciB))) lab = -1;
  }
  out[i] = (float)lab;
  float4 tt = make_float4(0.0f, 0.0f, 0.0f, 0.0f);
  if (inside) {
    int g = amax[i];
    float gx1 = gt[g*5], gy1 = gt[g*5+1], gx2 = gt[g*5+2], gy2 = gt[g*5+3];
    float ew = a.z - a.x + 1.0f, eh = a.w - a.y + 1.0f;
    float ecx = a.x + 0.5f * ew, ecy = a.y + 0.5f * eh;
    float gw = gx2 - gx1 + 1.0f, gh = gy2 - gy1 + 1.0f;
    float gcx = gx1 + 0.5f * gw, gcy = gy1 + 0.5f * gh;
    tt.x = (gcx - ecx) / ew;
    tt.y = (gcy - ecy) / eh;
    tt.z = logf(gw / ew);
    tt.w = logf(gh / eh);
  }
  ((float4*)(out + (size_t)N))[i] = tt;
  float iw = (lab == 1) ? 1.0f : 0.0f;
  ((float4*)(out + 5 * (size_t)N))[i] = make_float4(iw, iw, iw, iw);
  float ow = (lab == 0 || lab == 1) ? invw : 0.0f;
  ((float4*)(out + 9 * (size_t)N))[i] = make_float4(ow, ow, ow, ow);
}

extern "C" void kernel_launch(void* const* d_in, const int* in_sizes, int n_in,
                              void* d_out, int out_size, void* d_ws, size_t ws_size,
                              hipStream_t stream) {
  const float* gt      = (const float*)d_in[1];
  const float* im_info = (const float*)d_in[2];
  const float4* anchors = (const float4*)d_in[3];
  int N = in_sizes[3] / 4;             // 331776
  int G = in_sizes[1] / 5;             // 128
  if (G > GMAX) G = GMAX;
  const int A = 9;
  int HW = N / A;                      // 36864
  int W = (int)(sqrtf((float)HW) + 0.5f);  // 192
  int H = HW / W;                      // 192
  int ntx = (W + 15) / 16, nty = (H + 15) / 16;
  int ntiles = ntx * nty;              // 144
  int nGather = ntiles * A;            // 1296
  float* out = (float*)d_out;

  // ws: scalars, gt_max_s (G*A floats), amax, label (~1.7 MB)
  uint8_t* w = (uint8_t*)d_ws;
  uint32_t* scalars  = (uint32_t*)w;                 // 128 B
  float*    gt_max_s = (float*)(w + 4096);           // G*A*4 = 4608 B
  int*      amax     = (int*)(w + 16384);
  int8_t*   label    = (int8_t*)(w + 16384 + (size_t)N * 4);

  // staged in d_out's not-yet-final regions (k_output rewrites everything last)
  int*   fgIdx  = (int*)(out + (size_t)N);
  float* fgVal  = (float*)(out + 2 * (size_t)N);
  int*   bgcIdx = (int*)(out + 3 * (size_t)N);
  float* bgcVal = (float*)(out + 4 * (size_t)N);

  int nb = (N + 255) / 256;
  k_pre2<<<G * A + 1, 256, 0, stream>>>(anchors, gt, im_info, W, H, A, G,
                                        gt_max_s, scalars);
  k_work<<<nGather, 256, 0, stream>>>(anchors, gt, im_info, W, H, A, G, N, ntx,
                                      amax, label, gt_max_s, scalars,
                                      fgIdx, fgVal, bgcIdx, bgcVal);
  k_output<<<nb, 256, 0, stream>>>(anchors, gt, im_info, N, amax, label, scalars,
                                   fgIdx, fgVal, bgcIdx, bgcVal, out);
}

// Round 16
// 45.668 us; speedup vs baseline: 1.2211x; 1.2211x over previous
//
#include <hip/hip_runtime.h>
#include <stdint.h>

// AnchorTargetLayer for MI355X — 3-dispatch windowed gather.
// N = 331776 anchors (192*192*9 grid), G = 128 gt boxes.
// anchor(row,col,s) = base[s] + 16*(col,row,col,row) exactly in fp32, and
// base[s] == all_anchors[s]. Only ~2% of anchor-gt pairs have inter > 0.
// Pipeline:
//   k_pre2   block u=(g,s): per-(gt,shape) window max -> PLAIN store
//            gt_max_s[u] (no atomics, no init); last block zeros scalars
//   k_work   432 blocks = (16x16-cell tile) x (shape-group of 3):
//            per-anchor best/argmax + INLINE tie test + label + RNG +
//            fg list + bg candidates
//   k_output every block recomputes the exact lex cutoffs from the lists
//            (LDS-cached) then writes labels/targets/weights
// NOTE r9:  cooperative grid.sync() ~100us/sync on gfx950 — never.
// NOTE r11: per-block __threadfence() = L2-writeback storm (+80us/432 blks)
//           — kernel boundaries ARE the cheap fence.
// NOTE r12: serializing a small-grid pre-pass costs ~8us; keep pre-passes
//           wide (>=1000 blocks) and tiny.
// NOTE r15: k_work granularity measured: 144 blocks=49.6us, 432=46.2us,
//           1296=55.8us — 432 (3 shapes/thread) is the minimum; block-fixed
//           gt-list overhead dominates past that.
#define TF_PARTITIONABLE 1

#define GMAX 128
#define FG_CAP 8192
#define BGC_CAP 8192
#define LDS_CAP 2048
#define T1 0.00390625f        // bg candidate threshold = 1/256
                              // cutoff quantile ~256/200k=0.0013; candidates
                              // ~Binom(200k,1/256)=781±28 -> 18 sigma >= k_b
#define RPN_NEG 0.3f
#define RPN_POS 0.7f

struct U2 { uint32_t a, b; };

__host__ __device__ constexpr U2 tf2x32(uint32_t k0, uint32_t k1, uint32_t x0, uint32_t x1) {
  uint32_t ks2 = k0 ^ k1 ^ 0x1BD11BDAu;
  x0 += k0; x1 += k1;
#define TFR(r) { x0 += x1; x1 = (uint32_t)((x1 << (r)) | (x1 >> (32 - (r)))); x1 ^= x0; }
  TFR(13) TFR(15) TFR(26) TFR(6)
  x0 += k1; x1 += ks2 + 1u;
  TFR(17) TFR(29) TFR(16) TFR(24)
  x0 += ks2; x1 += k0 + 2u;
  TFR(13) TFR(15) TFR(26) TFR(6)
  x0 += k0; x1 += k1 + 3u;
  TFR(17) TFR(29) TFR(16) TFR(24)
  x0 += k1; x1 += ks2 + 4u;
  TFR(13) TFR(15) TFR(26) TFR(6)
  x0 += ks2; x1 += k0 + 5u;
#undef TFR
  return U2{x0, x1};
}

#if TF_PARTITIONABLE
constexpr U2 KEYF = tf2x32(0u, 42u, 0u, 0u);
constexpr U2 KEYB = tf2x32(0u, 42u, 0u, 1u);
#else
constexpr U2 C02 = tf2x32(0u, 42u, 0u, 2u);
constexpr U2 C13 = tf2x32(0u, 42u, 1u, 3u);
constexpr U2 KEYF = U2{C02.a, C13.a};
constexpr U2 KEYB = U2{C02.b, C13.b};
#endif

__device__ __forceinline__ float tf_uniform(uint32_t k0, uint32_t k1, uint32_t i, uint32_t N) {
#if TF_PARTITIONABLE
  U2 r = tf2x32(k0, k1, 0u, i);
  uint32_t bits = r.a ^ r.b;
#else
  uint32_t h = N >> 1;
  uint32_t bits;
  if (i < h) { U2 r = tf2x32(k0, k1, i, i + h); bits = r.a; }
  else       { U2 r = tf2x32(k0, k1, i - h, i); bits = r.b; }
#endif
  return __uint_as_float((bits >> 9) | 0x3f800000u) - 1.0f;
}

// window of cells where inter COULD be >0 for box B vs gt, with ±1 slack
__device__ __forceinline__ void window(float4 B, float gx1, float gy1, float gx2, float gy2,
                                       int W, int H, int& c0, int& c1, int& r0, int& r1) {
  c0 = (int)floorf((gx1 - 1.0f - B.z) * 0.0625f) - 1; if (c0 < 0) c0 = 0;
  c1 = (int)ceilf ((gx2 + 1.0f - B.x) * 0.0625f) + 1; if (c1 > W - 1) c1 = W - 1;
  r0 = (int)floorf((gy1 - 1.0f - B.w) * 0.0625f) - 1; if (r0 < 0) r0 = 0;
  r1 = (int)ceilf ((gy2 + 1.0f - B.y) * 0.0625f) + 1; if (r1 > H - 1) r1 = H - 1;
}

// wave-aggregated append slot: 1 LDS atomic per wave; all lanes must call
__device__ __forceinline__ uint32_t waveAppend(uint32_t* lds_cnt, bool pred) {
  unsigned long long m = __ballot(pred);
  uint32_t my = 0u;
  if (m) {
    int lane = (int)(threadIdx.x & 63);
    int lead = __ffsll(m) - 1;
    uint32_t rank = (uint32_t)__popcll(m & ((1ull << lane) - 1ull));
    uint32_t base = 0u;
    if (lane == lead) base = atomicAdd(lds_cnt, (uint32_t)__popcll(m));
    base = __shfl(base, lead);
    my = base + rank;
  }
  return my;
}

// scalars layout (u32): 0 F | 1 B | 2 bgcCnt

// K1: blocks [0, G*A) = per-(gt,shape) window max, PLAIN store (no init);
//     block G*A zeros scalars.
__global__ __launch_bounds__(256) void k_pre2(const float4* __restrict__ anchors,
    const float* __restrict__ gt, const float* __restrict__ im_info,
    int W, int H, int A, int G,
    float* __restrict__ gt_max_s, uint32_t* __restrict__ scalars) {
#pragma clang fp contract(off)
  int t = threadIdx.x;
  if (blockIdx.x == (unsigned)(G * A)) {
    if (t < 32) scalars[t] = 0u;
    return;
  }
  int g = blockIdx.x / A, s = blockIdx.x % A;
  float4 B = anchors[s];
  float gx1 = gt[g*5], gy1 = gt[g*5+1], gx2 = gt[g*5+2], gy2 = gt[g*5+3];
  float ga = (gx2 - gx1 + 1.0f) * (gy2 - gy1 + 1.0f);
  float aa = (B.z - B.x + 1.0f) * (B.w - B.y + 1.0f);
  float imH = im_info[0], imW = im_info[1];
  int c0, c1, r0, r1;
  window(B, gx1, gy1, gx2, gy2, W, H, c0, c1, r0, r1);
  float m = -1.0f;
  if (c1 >= c0 && r1 >= r0) {
    int wc = c1 - c0 + 1, tot = wc * (r1 - r0 + 1);
    for (int idx = t; idx < tot; idx += 256) {
      int row = r0 + idx / wc, col = c0 + idx % wc;
      float fx = 16.0f * (float)col, fy = 16.0f * (float)row;
      float ax = B.x + fx, ay = B.y + fy, az = B.z + fx, aw = B.w + fy;
      if (!(ax >= 0.0f && ay >= 0.0f && az < imW && aw < imH)) continue;
      float iwr = fminf(az, gx2) - fmaxf(ax, gx1) + 1.0f;
      float ihr = fminf(aw, gy2) - fmaxf(ay, gy1) + 1.0f;
      if (iwr > 0.0f && ihr > 0.0f) {
        float inter = iwr * ihr;                      // clamped product (both >0)
        m = fmaxf(m, inter / ((aa + ga) - inter));    // reference bit sequence
      }
    }
  }
#pragma unroll
  for (int d = 1; d < 64; d <<= 1) m = fmaxf(m, __shfl_xor(m, d));
  __shared__ float wm[4];
  if ((t & 63) == 0) wm[t >> 6] = m;
  __syncthreads();
  if (t == 0)
    gt_max_s[blockIdx.x] = fmaxf(fmaxf(wm[0], wm[1]), fmaxf(wm[2], wm[3]));
}

// K2: gather tiles (tile x shape-group of 3); inline tie test; NO tail.
__global__ __launch_bounds__(256) void k_work(const float4* __restrict__ anchors,
    const float* __restrict__ gt, const float* __restrict__ im_info,
    int W, int H, int A, int G, int N, int ntx,
    int* __restrict__ amax, int8_t* __restrict__ label,
    const float* __restrict__ gt_max_s, uint32_t* __restrict__ scalars,
    int* __restrict__ fgIdx, float* __restrict__ fgVal,
    int* __restrict__ bgcIdx, float* __restrict__ bgcVal) {
#pragma clang fp contract(off)
  __shared__ float4 sgt4[GMAX];
  __shared__ float sga[GMAX];
  __shared__ float sgm[GMAX];
  __shared__ int slist[GMAX];
  __shared__ float4 sB[3];
  __shared__ float sBa[3];
  __shared__ float4 sBu;
  __shared__ uint32_t wcnt[4];
  __shared__ uint32_t lcnt[3], lbase[2];   // 0 fg, 1 bg-cand, 2 bg total
  int t = threadIdx.x;
  int tile = blockIdx.x / 3, sg = blockIdx.x % 3;
  int tc = tile % ntx, tr = tile / ntx;
  float imH = im_info[0], imW = im_info[1];
  if (t < 3) {
    lcnt[t] = 0u;
    float4 bb = anchors[sg * 3 + t];
    sB[t] = bb;
    sBa[t] = (bb.z - bb.x + 1.0f) * (bb.w - bb.y + 1.0f);
  }
  if (t == 0) {
    float4 u = anchors[0];
    for (int s = 1; s < A; ++s) {
      float4 bb = anchors[s];
      u.x = fminf(u.x, bb.x); u.y = fminf(u.y, bb.y);
      u.z = fmaxf(u.z, bb.z); u.w = fmaxf(u.w, bb.w);
    }
    sBu = u;
  }
  __syncthreads();
  // per-tile gt list, ballot-compacted ascending (union window over shapes)
  bool fl = false;
  if (t < G) {
    int c0, c1, r0, r1;
    window(sBu, gt[t*5], gt[t*5+1], gt[t*5+2], gt[t*5+3], W, H, c0, c1, r0, r1);
    fl = (c1 >= c0 && r1 >= r0 &&
          c0 <= tc*16+15 && c1 >= tc*16 && r0 <= tr*16+15 && r1 >= tr*16);
  }
  unsigned long long bm = __ballot(fl);
  int wv = t >> 6, ln = t & 63;
  if (ln == 0) wcnt[wv] = (uint32_t)__popcll(bm);
  __syncthreads();
  int cnt = (int)(wcnt[0] + wcnt[1]);     // G <= 128
  if (fl) {
    uint32_t base = (wv == 1) ? wcnt[0] : 0u;
    uint32_t rank = (uint32_t)__popcll(bm & ((1ull << ln) - 1ull));
    slist[base + rank] = t;
  }
  __syncthreads();
  for (int q = t; q < cnt; q += 256) {
    int g = slist[q];
    float x1 = gt[g*5], y1 = gt[g*5+1], x2 = gt[g*5+2], y2 = gt[g*5+3];
    sgt4[q] = make_float4(x1, y1, x2, y2);
    sga[q] = (x2 - x1 + 1.0f) * (y2 - y1 + 1.0f);
    // fold per-shape maxima: fmaxf exactly associative -> bit-identical
    float gm = gt_max_s[g * A];
    for (int s = 1; s < A; ++s) gm = fmaxf(gm, gt_max_s[g * A + s]);
    sgm[q] = gm;
  }
  __syncthreads();

  int col = tc * 16 + (t & 15), row = tr * 16 + (t >> 4);
  bool validCell = (col < W) && (row < H);
  float fx = 16.0f * (float)col, fy = 16.0f * (float)row;   // exact integers
  if (!validCell) { fx = -1.0e9f; fy = -1.0e9f; }
  float ax[3], ay[3], az[3], aw[3], aab[3], best[3];
  int am[3];
  bool tie[3] = {false, false, false};
  uint32_t insM = 0u;
#pragma unroll
  for (int k = 0; k < 3; ++k) {
    float4 bb = sB[k];
    ax[k] = bb.x + fx; ay[k] = bb.y + fy;   // == reference anchor bits
    az[k] = bb.z + fx; aw[k] = bb.w + fy;
    aab[k] = sBa[k];
    if (ax[k] >= 0.0f && ay[k] >= 0.0f && az[k] < imW && aw[k] < imH) insM |= 1u << k;
    best[k] = 0.0f; am[k] = 0;              // all-zero row -> argmax 0 (reference)
  }
  for (int q = 0; q < cnt; ++q) {           // ascending g: first-max rule
    float4 G4 = sgt4[q];
    float ga = sga[q];
    float gm = sgm[q];
    int g = slist[q];
#pragma unroll
    for (int k = 0; k < 3; ++k) {
      float iwr = fminf(az[k], G4.z) - fmaxf(ax[k], G4.x) + 1.0f;
      float ihr = fminf(aw[k], G4.w) - fmaxf(ay[k], G4.y) + 1.0f;
      float inter = fmaxf(iwr, 0.0f) * fmaxf(ihr, 0.0f);
      float v = inter / ((aab[k] + ga) - inter);   // inter==0 -> v==+0.0 exact
      if (v > best[k]) { best[k] = v; am[k] = g; }
      tie[k] |= (v == gm);                          // is_best: v matches col max
    }
  }
  // finalize: label (quirk order), amax, RNG, list appends
  int clsA[3]; float valA[3]; uint32_t myA[3];
#pragma unroll
  for (int k = 0; k < 3; ++k) {
    int s = sg * 3 + k;
    int i = (row * W + col) * A + s;
    bool ins = (insM >> k) & 1u;
    int lab = -1;
    if (ins) {
      if (best[k] < RPN_NEG) lab = 0;
      if (tie[k]) lab = -lab;                 // -1 -> 1 ; 0 stays 0 (quirk)
      if (best[k] >= RPN_POS) lab = 1;
    }
    bool isf = validCell && (lab == 1);
    bool isb = validCell && (lab == 0);
    if (validCell) { label[i] = (int8_t)lab; amax[i] = am[k]; }
    float val = 0.0f;
    if (isf) val = tf_uniform(KEYF.a, KEYF.b, (uint32_t)i, (uint32_t)N);
    if (isb) val = tf_uniform(KEYB.a, KEYB.b, (uint32_t)i, (uint32_t)N);
    bool cand = isb && (val < T1);
    unsigned long long mb = __ballot(isb);           // bg total via ballot count
    if ((t & 63) == 0 && mb) atomicAdd(&lcnt[2], (uint32_t)__popcll(mb));
    uint32_t mf = waveAppend(&lcnt[0], isf);
    uint32_t mc = waveAppend(&lcnt[1], cand);
    clsA[k] = isf ? 0 : (cand ? 1 : -1);
    valA[k] = val;
    myA[k] = isf ? mf : mc;
  }
  __syncthreads();
  if (t == 0) {
    lbase[0] = lcnt[0] ? atomicAdd(&scalars[0], lcnt[0]) : 0u;
    lbase[1] = lcnt[1] ? atomicAdd(&scalars[2], lcnt[1]) : 0u;
    if (lcnt[2]) atomicAdd(&scalars[1], lcnt[2]);
  }
  __syncthreads();
#pragma unroll
  for (int k = 0; k < 3; ++k) {
    int s = sg * 3 + k;
    int i = (row * W + col) * A + s;
    if (clsA[k] == 0) {
      uint32_t p = lbase[0] + myA[k];
      if (p < FG_CAP) { fgIdx[p] = i; fgVal[p] = valA[k]; }
    } else if (clsA[k] == 1) {
      uint32_t p = lbase[1] + myA[k];
      if (p < BGC_CAP) { bgcIdx[p] = i; bgcVal[p] = valA[k]; }
    }
  }
}

// K3: every block recomputes the exact lex cutoffs (deterministic; lists
// LDS-cached when <= LDS_CAP entries), then writes labels/targets/weights.
__global__ __launch_bounds__(256) void k_output(const float4* __restrict__ anchors,
    const float* __restrict__ gt, const float* __restrict__ im_info, int N,
    const int* __restrict__ amax, const int8_t* __restrict__ label,
    const uint32_t* __restrict__ scalars,
    const int* __restrict__ fgIdx, const float* __restrict__ fgVal,
    const int* __restrict__ bgcIdx, const float* __restrict__ bgcVal,
    float* __restrict__ out) {
#pragma clang fp contract(off)
  __shared__ float lv[LDS_CAP];
  __shared__ int   li[LDS_CAP];
  __shared__ uint32_t hist[256];
  __shared__ int binT; __shared__ uint32_t baseT;
  __shared__ int mcnt;
  __shared__ float mv[256]; __shared__ int mi[256]; __shared__ uint32_t mr[256];
  __shared__ float s_cv[2]; __shared__ int s_ci[2]; __shared__ float s_inv;
  int t = threadIdx.x;
  uint32_t F = scalars[0], B = scalars[1];
  uint32_t k_f = F > 128u ? 128u : F;
  uint32_t k_b = 256u - k_f;
  if (t == 0) {
    uint32_t kept = k_f + (B < k_b ? B : k_b);
    s_inv = kept ? (1.0f / (float)kept) : 0.0f;       // 1/num_ex
    s_cv[0] = __uint_as_float(0x7f800000u); s_ci[0] = 0x7fffffff;  // keep-all
    s_cv[1] = __uint_as_float(0x7f800000u); s_ci[1] = 0x7fffffff;
  }
  __syncthreads();
  for (int pass = 0; pass < 2; ++pass) {
    const float* gvals = pass ? bgcVal : fgVal;
    const int*   gidxs = pass ? bgcIdx : fgIdx;
    uint32_t tot = pass ? B : F;
    uint32_t kk  = pass ? k_b : k_f;
    uint32_t rawn = pass ? scalars[2] : F;
    uint32_t cap  = pass ? (uint32_t)BGC_CAP : (uint32_t)FG_CAP;
    int n = (int)(rawn > cap ? cap : rawn);
    float scale = pass ? (256.0f / T1) : 256.0f;
    bool need = (tot > kk) && (kk > 0u) && ((uint32_t)n >= kk);
    bool useLds = need && (n <= LDS_CAP);
    if (useLds)
      for (int j = t; j < n; j += 256) { lv[j] = gvals[j]; li[j] = gidxs[j]; }
    const float* vals = useLds ? (const float*)lv : gvals;
    const int*   idxs = useLds ? (const int*)li : gidxs;
    hist[t] = 0u;
    if (t == 0) { mcnt = 0; binT = -1; baseT = 0u; }
    __syncthreads();
    if (need)
      for (int j = t; j < n; j += 256) {
        int b = (int)(vals[j] * scale); if (b > 255) b = 255;
        atomicAdd(&hist[b], 1u);
      }
    __syncthreads();
    if (need && t == 0) {
      uint32_t c = 0;
      for (int b = 0; b < 256; ++b) {
        if (c + hist[b] >= kk) { binT = b; baseT = c; break; }
        c += hist[b];
      }
    }
    __syncthreads();
    if (need)
      for (int j = t; j < n; j += 256) {
        int b = (int)(vals[j] * scale); if (b > 255) b = 255;
        if (b == binT) {
          int p = atomicAdd(&mcnt, 1);
          if (p < 256) { mv[p] = vals[j]; mi[p] = idxs[j]; }
        }
      }
    __syncthreads();
    int m = mcnt > 256 ? 256 : mcnt;
    if (t < m) mr[t] = baseT;
    __syncthreads();
    if (need)
      for (int j = t; j < n; j += 256) {
        float v = vals[j]; int i = idxs[j];
        int b = (int)(v * scale); if (b > 255) b = 255;
        if (b == binT)
          for (int q = 0; q < m; ++q)
            if (v < mv[q] || (v == mv[q] && i < mi[q])) atomicAdd(&mr[q], 1u);
      }
    __syncthreads();
    if (need && t < m && mr[t] == kk - 1u) { s_cv[pass] = mv[t]; s_ci[pass] = mi[t]; }
    __syncthreads();
  }

  float invw = s_inv;
  float cvF = s_cv[0]; int ciF = s_ci[0];
  float cvB = s_cv[1]; int ciB = s_ci[1];
  int i = blockIdx.x * 256 + t;
  if (i >= N) return;
  float4 a = anchors[i];
  float imH = im_info[0], imW = im_info[1];
  bool inside = (a.x >= 0.0f && a.y >= 0.0f && a.z < imW && a.w < imH);
  int lab = label[i];
  if (lab == 1) {                 // fg subsample: keep iff (v,i) <=lex cutF
    float v = tf_uniform(KEYF.a, KEYF.b, (uint32_t)i, (uint32_t)N);
    if (!(v < cvF || (v == cvF && i <= ciF))) lab = -1;
  } else if (lab == 0) {          // bg subsample
    float v = tf_uniform(KEYB.a, KEYB.b, (uint32_t)i, (uint32_t)N);
    if (!(v < cvB || (v == cvB && i <= ciB))) lab = -1;
  }
  out[i] = (float)lab;
  float4 tt = make_float4(0.0f, 0.0f, 0.0f, 0.0f);
  if (inside) {
    int g = amax[i];
    float gx1 = gt[g*5], gy1 = gt[g*5+1], gx2 = gt[g*5+2], gy2 = gt[g*5+3];
    float ew = a.z - a.x + 1.0f, eh = a.w - a.y + 1.0f;
    float ecx = a.x + 0.5f * ew, ecy = a.y + 0.5f * eh;
    float gw = gx2 - gx1 + 1.0f, gh = gy2 - gy1 + 1.0f;
    float gcx = gx1 + 0.5f * gw, gcy = gy1 + 0.5f * gh;
    tt.x = (gcx - ecx) / ew;
    tt.y = (gcy - ecy) / eh;
    tt.z = logf(gw / ew);
    tt.w = logf(gh / eh);
  }
  ((float4*)(out + (size_t)N))[i] = tt;
  float iw = (lab == 1) ? 1.0f : 0.0f;
  ((float4*)(out + 5 * (size_t)N))[i] = make_float4(iw, iw, iw, iw);
  float ow = (lab == 0 || lab == 1) ? invw : 0.0f;
  ((float4*)(out + 9 * (size_t)N))[i] = make_float4(ow, ow, ow, ow);
}

extern "C" void kernel_launch(void* const* d_in, const int* in_sizes, int n_in,
                              void* d_out, int out_size, void* d_ws, size_t ws_size,
                              hipStream_t stream) {
  const float* gt      = (const float*)d_in[1];
  const float* im_info = (const float*)d_in[2];
  const float4* anchors = (const float4*)d_in[3];
  int N = in_sizes[3] / 4;             // 331776
  int G = in_sizes[1] / 5;             // 128
  if (G > GMAX) G = GMAX;
  const int A = 9;
  int HW = N / A;                      // 36864
  int W = (int)(sqrtf((float)HW) + 0.5f);  // 192
  int H = HW / W;                      // 192
  int ntx = (W + 15) / 16, nty = (H + 15) / 16;
  int ntiles = ntx * nty;              // 144
  int nGather = ntiles * 3;            // 432
  float* out = (float*)d_out;

  // ws: scalars, gt_max_s (G*A floats), amax, label (~1.7 MB)
  uint8_t* w = (uint8_t*)d_ws;
  uint32_t* scalars  = (uint32_t*)w;                 // 128 B
  float*    gt_max_s = (float*)(w + 4096);           // G*A*4 = 4608 B
  int*      amax     = (int*)(w + 16384);
  int8_t*   label    = (int8_t*)(w + 16384 + (size_t)N * 4);

  // staged in d_out's not-yet-final regions (k_output rewrites everything last)
  int*   fgIdx  = (int*)(out + (size_t)N);
  float* fgVal  = (float*)(out + 2 * (size_t)N);
  int*   bgcIdx = (int*)(out + 3 * (size_t)N);
  float* bgcVal = (float*)(out + 4 * (size_t)N);

  int nb = (N + 255) / 256;
  k_pre2<<<G * A + 1, 256, 0, stream>>>(anchors, gt, im_info, W, H, A, G,
                                        gt_max_s, scalars);
  k_work<<<nGather, 256, 0, stream>>>(anchors, gt, im_info, W, H, A, G, N, ntx,
                                      amax, label, gt_max_s, scalars,
                                      fgIdx, fgVal, bgcIdx, bgcVal);
  k_output<<<nb, 256, 0, stream>>>(anchors, gt, im_info, N, amax, label, scalars,
                                   fgIdx, fgVal, bgcIdx, bgcVal, out);
}